// Round 1
// baseline (2677.702 us; speedup 1.0000x reference)
//
#include <hip/hip_runtime.h>
#include <cstdint>
#include <cstddef>

// Shapes: B=8, N=1024, DIM=512, HEADS=8, DH=64, HD=512, FF=2048, DEPTH=4
// Workspace budget ~237 MB (see offsets in kernel_launch).

typedef __attribute__((ext_vector_type(8))) short bf8v;   // 8 x bf16 (4 VGPR)
typedef __attribute__((ext_vector_type(4))) float f4v;    // mfma accumulator

#define MFMA16(a, b, c) __builtin_amdgcn_mfma_f32_16x16x32_bf16((a), (b), (c), 0, 0, 0)

static __device__ __forceinline__ float b2f(unsigned short u) {
  union { float f; unsigned int i; } x; x.i = ((unsigned int)u) << 16; return x.f;
}
static __device__ __forceinline__ unsigned short f2b(float f) {
  union { float f; unsigned int i; } x; x.f = f;
  unsigned int r = x.i + 0x7fffu + ((x.i >> 16) & 1u);  // round-to-nearest-even
  return (unsigned short)(r >> 16);
}

// ---------- weight transpose+convert: src f32 (L,K,N) -> dst bf16 (L,N,K) ----------
__global__ __launch_bounds__(256) void wconv_kernel(const float* __restrict__ src,
                                                    unsigned short* __restrict__ dst,
                                                    int K, int N) {
  src += (size_t)blockIdx.z * K * N;
  dst += (size_t)blockIdx.z * K * N;
  __shared__ float t[32][33];
  int n0 = blockIdx.x * 32, k0 = blockIdx.y * 32;
  int c = threadIdx.x & 31, r = threadIdx.x >> 5;
#pragma unroll
  for (int rr = r; rr < 32; rr += 8) t[rr][c] = src[(size_t)(k0 + rr) * N + n0 + c];
  __syncthreads();
#pragma unroll
  for (int rr = r; rr < 32; rr += 8) dst[(size_t)(n0 + rr) * K + k0 + c] = f2b(t[c][rr]);
}

// ---------- flat f32 -> bf16 convert (n8 = elems/8) ----------
__global__ __launch_bounds__(256) void conv_kernel(const float* __restrict__ src,
                                                   unsigned short* __restrict__ dst, int n8) {
  int i = blockIdx.x * 256 + threadIdx.x;
  if (i >= n8) return;
  float4 a = ((const float4*)src)[i * 2];
  float4 b = ((const float4*)src)[i * 2 + 1];
  bf8v o;
  o[0] = (short)f2b(a.x); o[1] = (short)f2b(a.y); o[2] = (short)f2b(a.z); o[3] = (short)f2b(a.w);
  o[4] = (short)f2b(b.x); o[5] = (short)f2b(b.y); o[6] = (short)f2b(b.z); o[7] = (short)f2b(b.w);
  *(bf8v*)(dst + (size_t)i * 8) = o;
}

// ---------- LayerNorm over rows of 512: f32 -> bf16, one wave per row ----------
__global__ __launch_bounds__(256) void ln_kernel(const float* __restrict__ x,
                                                 const float* __restrict__ g,
                                                 const float* __restrict__ bb,
                                                 unsigned short* __restrict__ out) {
  int row = blockIdx.x * 4 + (threadIdx.x >> 6);
  int l = threadIdx.x & 63;
  const float* xr = x + (size_t)row * 512;
  float4 a = *(const float4*)(xr + l * 8);
  float4 b = *(const float4*)(xr + l * 8 + 4);
  float s = a.x + a.y + a.z + a.w + b.x + b.y + b.z + b.w;
  float q = a.x*a.x + a.y*a.y + a.z*a.z + a.w*a.w + b.x*b.x + b.y*b.y + b.z*b.z + b.w*b.w;
#pragma unroll
  for (int off = 32; off >= 1; off >>= 1) { s += __shfl_xor(s, off); q += __shfl_xor(q, off); }
  float mean = s * (1.0f / 512.0f);
  float var = q * (1.0f / 512.0f) - mean * mean;
  float rs = rsqrtf(var + 1e-5f);
  float vals[8] = {a.x, a.y, a.z, a.w, b.x, b.y, b.z, b.w};
  bf8v o;
#pragma unroll
  for (int e = 0; e < 8; ++e) {
    int cc = l * 8 + e;
    o[e] = (short)f2b((vals[e] - mean) * rs * g[cc] + bb[cc]);
  }
  *(bf8v*)(out + (size_t)row * 512 + l * 8) = o;
}

// ---------- generic NT bf16 GEMM: C[M,N] = A[M,K] @ Bt[N,K]^T ----------
// 128x128 tile, BK=32, 4 waves (2x2 of 64x64), 16x16x32 MFMA, padded LDS rows (40).
enum { EPI_BF16 = 0, EPI_QKV = 1, EPI_GELU = 2, EPI_RES = 3 };

template <int EPI>
__global__ __launch_bounds__(256, 2) void gemm_kernel(
    const unsigned short* __restrict__ A, int lda, long aOffB, long aOffH,
    const unsigned short* __restrict__ Bt, int ldb, long bOffB, long bOffH,
    void* __restrict__ Cv, int ldc, long cOffZ,
    int K, const float* __restrict__ bias, const float* __restrict__ resid) {
  int z = blockIdx.z;
  int zb = z >> 3, zh = z & 7;
  A += (size_t)zb * aOffB + (size_t)zh * aOffH;
  Bt += (size_t)zb * bOffB + (size_t)zh * bOffH;
  int m0 = blockIdx.y * 128, n0 = blockIdx.x * 128;
  int tid = threadIdx.x, w = tid >> 6, l = tid & 63;
  int wm = w >> 1, wn = w & 1;
  int lr = l & 15, lg = l >> 4;
  __shared__ unsigned short As[128 * 40];
  __shared__ unsigned short Bs[128 * 40];
  f4v acc[4][4];
#pragma unroll
  for (int m = 0; m < 4; ++m)
#pragma unroll
    for (int n = 0; n < 4; ++n) acc[m][n] = f4v{0.f, 0.f, 0.f, 0.f};

  for (int k0 = 0; k0 < K; k0 += 32) {
#pragma unroll
    for (int it = 0; it < 4; ++it) {
      int c = tid + 256 * it;
      int cc = c & 511, rr = cc >> 2, pp = cc & 3;
      const unsigned short* src = (c < 512) ? (A + (size_t)(m0 + rr) * lda + k0 + pp * 8)
                                            : (Bt + (size_t)(n0 + rr) * ldb + k0 + pp * 8);
      unsigned short* dl = ((c < 512) ? As : Bs) + rr * 40 + pp * 8;
      *(bf8v*)dl = *(const bf8v*)src;
    }
    __syncthreads();
    bf8v af[4], bf[4];
#pragma unroll
    for (int m = 0; m < 4; ++m) af[m] = *(bf8v*)&As[(wm * 64 + m * 16 + lr) * 40 + lg * 8];
#pragma unroll
    for (int n = 0; n < 4; ++n) bf[n] = *(bf8v*)&Bs[(wn * 64 + n * 16 + lr) * 40 + lg * 8];
#pragma unroll
    for (int m = 0; m < 4; ++m)
#pragma unroll
      for (int n = 0; n < 4; ++n) acc[m][n] = MFMA16(af[m], bf[n], acc[m][n]);
    __syncthreads();
  }
  // epilogue
#pragma unroll
  for (int m = 0; m < 4; ++m)
#pragma unroll
    for (int n = 0; n < 4; ++n) {
      int col = n0 + wn * 64 + n * 16 + lr;
#pragma unroll
      for (int r = 0; r < 4; ++r) {
        int row = m0 + wm * 64 + m * 16 + lg * 4 + r;
        float v = acc[m][n][r];
        size_t off = (size_t)cOffZ * z + (size_t)row * ldc + col;
        if (EPI == EPI_BF16) {
          ((unsigned short*)Cv)[off] = f2b(v);
        } else if (EPI == EPI_QKV) {
          if (col < 512) v += bias[col];
          ((unsigned short*)Cv)[off] = f2b(v);
        } else if (EPI == EPI_GELU) {
          v += bias[col];
          v = 0.5f * v * (1.0f + erff(v * 0.70710678118f));
          ((unsigned short*)Cv)[off] = f2b(v);
        } else {  // EPI_RES: f32 out = acc + bias + resid
          v += bias[col] + resid[off];
          ((float*)Cv)[off] = v;
        }
      }
    }
}

// ---------- transpose v: qkv[b][n][1024+h*64+d] -> vt[b][h][d][n] ----------
__global__ __launch_bounds__(256) void vtrans_kernel(const unsigned short* __restrict__ qkv,
                                                     unsigned short* __restrict__ vt) {
  int n0 = blockIdx.x * 32, h = blockIdx.y, b = blockIdx.z;
  __shared__ unsigned short t[32 * 72];
  int tid = threadIdx.x;
  {
    int r = tid >> 3, p = tid & 7;
    *(bf8v*)&t[r * 72 + p * 8] =
        *(const bf8v*)(qkv + (size_t)(b * 1024 + n0 + r) * 1536 + 1024 + h * 64 + p * 8);
  }
  __syncthreads();
  int d = tid >> 2, np = tid & 3;
  bf8v o;
#pragma unroll
  for (int e = 0; e < 8; ++e) o[e] = (short)t[(np * 8 + e) * 72 + d];
  *(bf8v*)(vt + ((size_t)(b * 512 + h * 64 + d)) * 1024 + n0 + np * 8) = o;
}

// ---------- fused attention: AC + shifted BD + head-softmax + PV (+ attn out) ----------
// block: (i-tile of 32 rows, b). 4 waves; wave w handles heads {w, w+4}.
template <bool LAST>
__global__ __launch_bounds__(256, 2) void attn_kernel(
    const unsigned short* __restrict__ qkv,  // [B][N][1536] (q has bias_pf)
    const unsigned short* __restrict__ vt,   // [B][8][64][N]
    const unsigned short* __restrict__ sp,   // [B*8][N][N]  Sp = qb . kr^T
    unsigned short* __restrict__ outp,       // [B][N][512]
    float* __restrict__ attn_out)            // [B][8][N][N] (LAST only)
{
  int i0 = blockIdx.x * 32, b = blockIdx.y;
  int tid = threadIdx.x, w = tid >> 6, l = tid & 63;
  int lr = l & 15, lg = l >> 4;
  __shared__ unsigned short stage[20480];        // q/k: [32][520]; v: [8][64][40]  (40KB)
  __shared__ unsigned short expv[8 * 32 * 40];   // exp tiles bf16, padded rows      (20KB)
  __shared__ unsigned short invd[32 * 32];       // 1/denom bf16                     (2KB)

  // stage q (biased) rows i0..i0+31, all heads
  for (int c = tid; c < 2048; c += 256) {
    int r = c >> 6, p = c & 63;
    *(bf8v*)&stage[r * 520 + p * 8] =
        *(const bf8v*)(qkv + (size_t)(b * 1024 + i0 + r) * 1536 + p * 8);
  }
  __syncthreads();
  bf8v qf[2][2][2];  // [head][m][ks]
#pragma unroll
  for (int hh = 0; hh < 2; ++hh) {
    int h = w + hh * 4;
#pragma unroll
    for (int m = 0; m < 2; ++m)
#pragma unroll
      for (int ks = 0; ks < 2; ++ks)
        qf[hh][m][ks] = *(bf8v*)&stage[(m * 16 + lr) * 520 + h * 64 + ks * 32 + lg * 8];
  }
  __syncthreads();

  f4v oacc[2][2][4];
#pragma unroll
  for (int hh = 0; hh < 2; ++hh)
#pragma unroll
    for (int m = 0; m < 2; ++m)
#pragma unroll
      for (int dt = 0; dt < 4; ++dt) oacc[hh][m][dt] = f4v{0.f, 0.f, 0.f, 0.f};

  for (int j0 = 0; j0 < 1024; j0 += 32) {
    // stage k
    for (int c = tid; c < 2048; c += 256) {
      int r = c >> 6, p = c & 63;
      *(bf8v*)&stage[r * 520 + p * 8] =
          *(const bf8v*)(qkv + (size_t)(b * 1024 + j0 + r) * 1536 + 512 + p * 8);
    }
    __syncthreads();
    // AC via MFMA
    f4v dacc[2][2][2];
#pragma unroll
    for (int hh = 0; hh < 2; ++hh) {
      int h = w + hh * 4;
      bf8v kf[2][2];
#pragma unroll
      for (int n = 0; n < 2; ++n)
#pragma unroll
        for (int ks = 0; ks < 2; ++ks)
          kf[n][ks] = *(bf8v*)&stage[(n * 16 + lr) * 520 + h * 64 + ks * 32 + lg * 8];
#pragma unroll
      for (int m = 0; m < 2; ++m)
#pragma unroll
        for (int n = 0; n < 2; ++n) {
          dacc[hh][m][n] = f4v{0.f, 0.f, 0.f, 0.f};
#pragma unroll
          for (int ks = 0; ks < 2; ++ks)
            dacc[hh][m][n] = MFMA16(qf[hh][m][ks], kf[n][ks], dacc[hh][m][n]);
        }
    }
    // dots = (AC + rel-shifted BD) * SCALE; exp -> expv
#pragma unroll
    for (int m = 0; m < 2; ++m)
#pragma unroll
      for (int n = 0; n < 2; ++n)
#pragma unroll
        for (int r = 0; r < 4; ++r) {
          int i = i0 + m * 16 + lg * 4 + r;
          int j = j0 + n * 16 + lr;
          int d = j - i;
          int roww = (d <= 0) ? i : i + 1;            // d>0 impossible at i=1023
          int cc = (d <= 0) ? d + 1023 : d - 2;
          if (cc < 0) cc = 0;                         // d==1 slot (value forced to 0)
          size_t base = (size_t)roww * 1024 + cc;
#pragma unroll
          for (int hh = 0; hh < 2; ++hh) {
            int h = w + hh * 4;
            float bd = (d == 1) ? 0.0f : b2f(sp[(((size_t)(b * 8 + h)) << 20) + base]);
            float dot = (dacc[hh][m][n][r] + bd) * 0.125f;
            expv[(h * 32 + m * 16 + lg * 4 + r) * 40 + n * 16 + lr] = f2b(__expf(dot));
          }
        }
    __syncthreads();
    // denominators over heads (+ last-layer attn output write)
#pragma unroll
    for (int e = 0; e < 4; ++e) {
      int p = tid + 256 * e, ii = p >> 5, jj = p & 31;
      float ev[8];
      float sum = 0.f;
#pragma unroll
      for (int h = 0; h < 8; ++h) { ev[h] = b2f(expv[(h * 32 + ii) * 40 + jj]); sum += ev[h]; }
      float inv = 1.0f / sum;
      invd[ii * 32 + jj] = f2b(inv);
      if (LAST) {
#pragma unroll
        for (int h = 0; h < 8; ++h)
          attn_out[((size_t)(b * 8 + h) * 1024 + i0 + ii) * 1024 + j0 + jj] = ev[h] * inv;
      }
    }
    // stage v^T tile [8][64][j0..j0+32] (reuses `stage`; k reads finished pre-barrier)
    for (int c = tid; c < 2048; c += 256) {
      int hd = c >> 2, p = c & 3;
      *(bf8v*)&stage[hd * 40 + p * 8] =
          *(const bf8v*)(vt + ((size_t)(b * 512 + hd)) * 1024 + j0 + p * 8);
    }
    __syncthreads();
    // PV via MFMA
#pragma unroll
    for (int hh = 0; hh < 2; ++hh) {
      int h = w + hh * 4;
      bf8v pf[2];
#pragma unroll
      for (int m = 0; m < 2; ++m) {
        int ir = m * 16 + lr;
        bf8v e8 = *(bf8v*)&expv[(h * 32 + ir) * 40 + lg * 8];
        bf8v pp;
#pragma unroll
        for (int e = 0; e < 8; ++e)
          pp[e] = (short)f2b(b2f((unsigned short)e8[e]) * b2f(invd[ir * 32 + lg * 8 + e]));
        pf[m] = pp;
      }
#pragma unroll
      for (int m = 0; m < 2; ++m)
#pragma unroll
        for (int dt = 0; dt < 4; ++dt) {
          bf8v vf = *(bf8v*)&stage[(h * 64 + dt * 16 + lr) * 40 + lg * 8];
          oacc[hh][m][dt] = MFMA16(pf[m], vf, oacc[hh][m][dt]);
        }
    }
    __syncthreads();
  }
  // write per-head outputs [B][N][512] bf16
#pragma unroll
  for (int hh = 0; hh < 2; ++hh) {
    int h = w + hh * 4;
#pragma unroll
    for (int m = 0; m < 2; ++m)
#pragma unroll
      for (int dt = 0; dt < 4; ++dt)
#pragma unroll
        for (int r = 0; r < 4; ++r) {
          int i = i0 + m * 16 + lg * 4 + r;
          int col = h * 64 + dt * 16 + lr;
          outp[(size_t)(b * 1024 + i) * 512 + col] = f2b(oacc[hh][m][dt][r]);
        }
  }
}

// =====================================================================================
extern "C" void kernel_launch(void* const* d_in, const int* in_sizes, int n_in,
                              void* d_out, int out_size, void* d_ws, size_t ws_size,
                              hipStream_t stream) {
  (void)in_sizes; (void)n_in; (void)out_size; (void)ws_size;
  const float* x_in   = (const float*)d_in[0];
  const float* r_t    = (const float*)d_in[1];
  const float* biaspf = (const float*)d_in[3];
  const float* ln1_g  = (const float*)d_in[4];
  const float* ln1_b  = (const float*)d_in[5];
  const float* Wqkv   = (const float*)d_in[6];
  const float* Wkr_t  = (const float*)d_in[7];
  const float* Wout   = (const float*)d_in[9];
  const float* bout   = (const float*)d_in[10];
  const float* ln2_g  = (const float*)d_in[11];
  const float* ln2_b  = (const float*)d_in[12];
  const float* W1     = (const float*)d_in[13];
  const float* b1     = (const float*)d_in[14];
  const float* W2     = (const float*)d_in[15];
  const float* b2     = (const float*)d_in[16];

  char* ws = (char*)d_ws;
  size_t off = 0;
  auto alloc = [&](size_t bytes) { char* p = ws + off; off += (bytes + 255) & ~(size_t)255; return p; };
  unsigned short* wt_qkv = (unsigned short*)alloc(4ull * 512 * 1536 * 2);
  unsigned short* wt_kr  = (unsigned short*)alloc(4ull * 512 * 512 * 2);
  unsigned short* wt_out = (unsigned short*)alloc(4ull * 512 * 512 * 2);
  unsigned short* wt_w1  = (unsigned short*)alloc(4ull * 512 * 2048 * 2);
  unsigned short* wt_w2  = (unsigned short*)alloc(4ull * 2048 * 512 * 2);
  unsigned short* rt_bf  = (unsigned short*)alloc(8192ull * 512 * 2);
  unsigned short* xn     = (unsigned short*)alloc(8192ull * 512 * 2);
  unsigned short* qkvb   = (unsigned short*)alloc(8192ull * 2048 * 2);  // union: qkv(1536) / ffh(2048)
  unsigned short* ffh    = qkvb;
  unsigned short* krb    = (unsigned short*)alloc(8192ull * 512 * 2);
  unsigned short* vtb    = (unsigned short*)alloc(8192ull * 512 * 2);
  unsigned short* spb    = (unsigned short*)alloc(64ull * 1024 * 1024 * 2);
  unsigned short* attnob = (unsigned short*)alloc(8192ull * 512 * 2);
  // total ~237 MB

  float* x      = (float*)d_out;              // running residual lives in d_out x-region
  float* attn_o = (float*)d_out + 4194304;    // [B][H][N][N]

  hipMemcpyAsync(x, x_in, 4194304ull * 4, hipMemcpyDeviceToDevice, stream);

  // weights -> bf16 transposed (N,K); r_t -> bf16
  wconv_kernel<<<dim3(48, 16, 4), 256, 0, stream>>>(Wqkv, wt_qkv, 512, 1536);
  wconv_kernel<<<dim3(16, 16, 4), 256, 0, stream>>>(Wkr_t, wt_kr, 512, 512);
  wconv_kernel<<<dim3(16, 16, 4), 256, 0, stream>>>(Wout, wt_out, 512, 512);
  wconv_kernel<<<dim3(64, 16, 4), 256, 0, stream>>>(W1, wt_w1, 512, 2048);
  wconv_kernel<<<dim3(16, 64, 4), 256, 0, stream>>>(W2, wt_w2, 2048, 512);
  conv_kernel<<<2048, 256, 0, stream>>>(r_t, rt_bf, 8192 * 512 / 8);

  for (int lyr = 0; lyr < 4; ++lyr) {
    // LN1
    ln_kernel<<<2048, 256, 0, stream>>>(x, ln1_g + lyr * 512, ln1_b + lyr * 512, xn);
    // QKV (+bias_pf on q cols)
    gemm_kernel<EPI_QKV><<<dim3(12, 64, 1), 256, 0, stream>>>(
        xn, 512, 0, 0, wt_qkv + (size_t)lyr * 512 * 1536, 512, 0, 0,
        qkvb, 1536, 0, 512, biaspf, nullptr);
    // kr_t = r_t @ Wkr_t
    gemm_kernel<EPI_BF16><<<dim3(4, 64, 1), 256, 0, stream>>>(
        rt_bf, 512, 0, 0, wt_kr + (size_t)lyr * 512 * 512, 512, 0, 0,
        krb, 512, 0, 512, nullptr, nullptr);
    // v^T
    vtrans_kernel<<<dim3(32, 8, 8), 256, 0, stream>>>(qkvb, vtb);
    // Sp[bh] = qb @ kr^T   (batched z = b*8+h)
    gemm_kernel<EPI_BF16><<<dim3(8, 8, 64), 256, 0, stream>>>(
        qkvb, 1536, 1024l * 1536, 64, krb, 512, 1024l * 512, 64,
        spb, 1024, 1024l * 1024, 64, nullptr, nullptr);
    // fused attention
    if (lyr == 3)
      attn_kernel<true><<<dim3(32, 8), 256, 0, stream>>>(qkvb, vtb, spb, attnob, attn_o);
    else
      attn_kernel<false><<<dim3(32, 8), 256, 0, stream>>>(qkvb, vtb, spb, attnob, nullptr);
    // x = attn_out @ Wout + bout + x
    gemm_kernel<EPI_RES><<<dim3(4, 64, 1), 256, 0, stream>>>(
        attnob, 512, 0, 0, wt_out + (size_t)lyr * 512 * 512, 512, 0, 0,
        x, 512, 0, 512, bout + lyr * 512, x);
    // LN2
    ln_kernel<<<2048, 256, 0, stream>>>(x, ln2_g + lyr * 512, ln2_b + lyr * 512, xn);
    // h = gelu(xn2 @ W1 + b1)
    gemm_kernel<EPI_GELU><<<dim3(16, 64, 1), 256, 0, stream>>>(
        xn, 512, 0, 0, wt_w1 + (size_t)lyr * 512 * 2048, 512, 0, 0,
        ffh, 2048, 0, 512, b1 + lyr * 2048, nullptr);
    // x = h @ W2 + b2 + x
    gemm_kernel<EPI_RES><<<dim3(4, 64, 1), 256, 0, stream>>>(
        ffh, 2048, 0, 0, wt_w2 + (size_t)lyr * 2048 * 512, 2048, 0, 0,
        x, 512, 0, 2048, b2 + lyr * 512, x);
  }
}

// Round 2
// 1678.877 us; speedup vs baseline: 1.5949x; 1.5949x over previous
//
#include <hip/hip_runtime.h>
#include <cstdint>
#include <cstddef>

// Shapes: B=8, N=1024, DIM=512, HEADS=8, DH=64, HD=512, FF=2048, DEPTH=4

typedef __attribute__((ext_vector_type(8))) short bf8v;   // 8 x bf16 (4 VGPR)
typedef __attribute__((ext_vector_type(4))) float f4v;    // mfma accumulator

#define MFMA16(a, b, c) __builtin_amdgcn_mfma_f32_16x16x32_bf16((a), (b), (c), 0, 0, 0)

static __device__ __forceinline__ float b2f(unsigned short u) {
  union { float f; unsigned int i; } x; x.i = ((unsigned int)u) << 16; return x.f;
}
static __device__ __forceinline__ unsigned short f2b(float f) {
  union { float f; unsigned int i; } x; x.f = f;
  unsigned int r = x.i + 0x7fffu + ((x.i >> 16) & 1u);  // round-to-nearest-even
  return (unsigned short)(r >> 16);
}

// ---------- weight transpose+convert: src f32 (L,K,N) -> dst bf16 (L,N,K) ----------
__global__ __launch_bounds__(256) void wconv_kernel(const float* __restrict__ src,
                                                    unsigned short* __restrict__ dst,
                                                    int K, int N) {
  src += (size_t)blockIdx.z * K * N;
  dst += (size_t)blockIdx.z * K * N;
  __shared__ float t[32][33];
  int n0 = blockIdx.x * 32, k0 = blockIdx.y * 32;
  int c = threadIdx.x & 31, r = threadIdx.x >> 5;
#pragma unroll
  for (int rr = r; rr < 32; rr += 8) t[rr][c] = src[(size_t)(k0 + rr) * N + n0 + c];
  __syncthreads();
#pragma unroll
  for (int rr = r; rr < 32; rr += 8) dst[(size_t)(n0 + rr) * K + k0 + c] = f2b(t[c][rr]);
}

// ---------- flat f32 -> bf16 convert (n8 = elems/8) ----------
__global__ __launch_bounds__(256) void conv_kernel(const float* __restrict__ src,
                                                   unsigned short* __restrict__ dst, int n8) {
  int i = blockIdx.x * 256 + threadIdx.x;
  if (i >= n8) return;
  float4 a = ((const float4*)src)[i * 2];
  float4 b = ((const float4*)src)[i * 2 + 1];
  bf8v o;
  o[0] = (short)f2b(a.x); o[1] = (short)f2b(a.y); o[2] = (short)f2b(a.z); o[3] = (short)f2b(a.w);
  o[4] = (short)f2b(b.x); o[5] = (short)f2b(b.y); o[6] = (short)f2b(b.z); o[7] = (short)f2b(b.w);
  *(bf8v*)(dst + (size_t)i * 8) = o;
}

// ---------- LayerNorm over rows of 512: f32 -> bf16, one wave per row ----------
__global__ __launch_bounds__(256) void ln_kernel(const float* __restrict__ x,
                                                 const float* __restrict__ g,
                                                 const float* __restrict__ bb,
                                                 unsigned short* __restrict__ out) {
  int row = blockIdx.x * 4 + (threadIdx.x >> 6);
  int l = threadIdx.x & 63;
  const float* xr = x + (size_t)row * 512;
  float4 a = *(const float4*)(xr + l * 8);
  float4 b = *(const float4*)(xr + l * 8 + 4);
  float s = a.x + a.y + a.z + a.w + b.x + b.y + b.z + b.w;
  float q = a.x*a.x + a.y*a.y + a.z*a.z + a.w*a.w + b.x*b.x + b.y*b.y + b.z*b.z + b.w*b.w;
#pragma unroll
  for (int off = 32; off >= 1; off >>= 1) { s += __shfl_xor(s, off); q += __shfl_xor(q, off); }
  float mean = s * (1.0f / 512.0f);
  float var = q * (1.0f / 512.0f) - mean * mean;
  float rs = rsqrtf(var + 1e-5f);
  float vals[8] = {a.x, a.y, a.z, a.w, b.x, b.y, b.z, b.w};
  bf8v o;
#pragma unroll
  for (int e = 0; e < 8; ++e) {
    int cc = l * 8 + e;
    o[e] = (short)f2b((vals[e] - mean) * rs * g[cc] + bb[cc]);
  }
  *(bf8v*)(out + (size_t)row * 512 + l * 8) = o;
}

// ---------- generic NT bf16 GEMM: C[M,N] = A[M,K] @ Bt[N,K]^T ----------
// 128x128 tile, BK=32, 4 waves (2x2 of 64x64), 16x16x32 MFMA, padded LDS rows (40).
enum { EPI_BF16 = 0, EPI_QKV = 1, EPI_GELU = 2, EPI_RES = 3, EPI_SHIFT = 4 };

template <int EPI>
__global__ __launch_bounds__(256, 2) void gemm_kernel(
    const unsigned short* __restrict__ A, int lda, long aOffB, long aOffH,
    const unsigned short* __restrict__ Bt, int ldb, long bOffB, long bOffH,
    void* __restrict__ Cv, int ldc, long cOffZ,
    int K, const float* __restrict__ bias, const float* __restrict__ resid) {
  int z = blockIdx.z;
  int zb = z >> 3, zh = z & 7;
  A += (size_t)zb * aOffB + (size_t)zh * aOffH;
  Bt += (size_t)zb * bOffB + (size_t)zh * bOffH;
  int m0 = blockIdx.y * 128, n0 = blockIdx.x * 128;
  int tid = threadIdx.x, w = tid >> 6, l = tid & 63;
  int wm = w >> 1, wn = w & 1;
  int lr = l & 15, lg = l >> 4;
  __shared__ unsigned short As[128 * 40];
  __shared__ unsigned short Bs[128 * 40];
  f4v acc[4][4];
#pragma unroll
  for (int m = 0; m < 4; ++m)
#pragma unroll
    for (int n = 0; n < 4; ++n) acc[m][n] = f4v{0.f, 0.f, 0.f, 0.f};

  for (int k0 = 0; k0 < K; k0 += 32) {
#pragma unroll
    for (int it = 0; it < 4; ++it) {
      int c = tid + 256 * it;
      int cc = c & 511, rr = cc >> 2, pp = cc & 3;
      const unsigned short* src = (c < 512) ? (A + (size_t)(m0 + rr) * lda + k0 + pp * 8)
                                            : (Bt + (size_t)(n0 + rr) * ldb + k0 + pp * 8);
      unsigned short* dl = ((c < 512) ? As : Bs) + rr * 40 + pp * 8;
      *(bf8v*)dl = *(const bf8v*)src;
    }
    __syncthreads();
    bf8v af[4], bf[4];
#pragma unroll
    for (int m = 0; m < 4; ++m) af[m] = *(bf8v*)&As[(wm * 64 + m * 16 + lr) * 40 + lg * 8];
#pragma unroll
    for (int n = 0; n < 4; ++n) bf[n] = *(bf8v*)&Bs[(wn * 64 + n * 16 + lr) * 40 + lg * 8];
#pragma unroll
    for (int m = 0; m < 4; ++m)
#pragma unroll
      for (int n = 0; n < 4; ++n) acc[m][n] = MFMA16(af[m], bf[n], acc[m][n]);
    __syncthreads();
  }
  // epilogue
#pragma unroll
  for (int m = 0; m < 4; ++m)
#pragma unroll
    for (int n = 0; n < 4; ++n) {
      int col = n0 + wn * 64 + n * 16 + lr;
#pragma unroll
      for (int r = 0; r < 4; ++r) {
        int row = m0 + wm * 64 + m * 16 + lg * 4 + r;
        float v = acc[m][n][r];
        size_t off = (size_t)cOffZ * z + (size_t)row * ldc + col;
        if (EPI == EPI_BF16) {
          ((unsigned short*)Cv)[off] = f2b(v);
        } else if (EPI == EPI_QKV) {
          if (col < 512) v += bias[col];
          ((unsigned short*)Cv)[off] = f2b(v);
        } else if (EPI == EPI_GELU) {
          v += bias[col];
          v = 0.5f * v * (1.0f + erff(v * 0.70710678118f));
          ((unsigned short*)Cv)[off] = f2b(v);
        } else if (EPI == EPI_RES) {  // f32 out = acc + bias + resid
          v += bias[col] + resid[off];
          ((float*)Cv)[off] = v;
        } else {  // EPI_SHIFT: scatter Sp(row,col) into rel-shifted BD layout
          // Sp[r,c] -> BD[r, r+c-1023] if c >= 1023-r ; BD[r-1, r+c+1] if r>=1, c<=1022-r.
          // BD[i, i+1] (the zero diagonal) is never written; attn gates it.
          unsigned short* bdp = (unsigned short*)Cv + (((size_t)z) << 20);
          if (col >= 1023 - row) {
            bdp[(size_t)row * 1024 + (row + col - 1023)] = f2b(v);
          } else if (row >= 1) {
            bdp[(size_t)(row - 1) * 1024 + (row + col + 1)] = f2b(v);
          }
        }
      }
    }
}

// ---------- transpose v: qkv[b][n][1024+h*64+d] -> vt[b][h][d][n] ----------
__global__ __launch_bounds__(256) void vtrans_kernel(const unsigned short* __restrict__ qkv,
                                                     unsigned short* __restrict__ vt) {
  int n0 = blockIdx.x * 32, h = blockIdx.y, b = blockIdx.z;
  __shared__ unsigned short t[32 * 72];
  int tid = threadIdx.x;
  {
    int r = tid >> 3, p = tid & 7;
    *(bf8v*)&t[r * 72 + p * 8] =
        *(const bf8v*)(qkv + (size_t)(b * 1024 + n0 + r) * 1536 + 1024 + h * 64 + p * 8);
  }
  __syncthreads();
  int d = tid >> 2, np = tid & 3;
  bf8v o;
#pragma unroll
  for (int e = 0; e < 8; ++e) o[e] = (short)t[(np * 8 + e) * 72 + d];
  *(bf8v*)(vt + ((size_t)(b * 512 + h * 64 + d)) * 1024 + n0 + np * 8) = o;
}

// ---------- fused attention v2: 8 waves (1 head each), j-chunked ----------
// grid (32 i-tiles, 2 j-chunks, 8 b), block 512.  BD pre-shifted in global.
// Per j-tile: coop BD->LDS || AC MFMA ; owner adds+exp in place ; denom pass
// normalizes in place (+ attn out on last layer) ; PV MFMA from LDS P.
template <bool LAST>
__global__ __launch_bounds__(512, 4) void attn_kernel(
    const unsigned short* __restrict__ qkv,  // [B][N][1536] (q has bias_pf)
    const unsigned short* __restrict__ vt,   // [B][8][64][N]
    const unsigned short* __restrict__ bd,   // [B*8][N][N]  shifted BD (d==1 col garbage)
    unsigned short* __restrict__ pvpart,     // [JC=2][B][N][512] bf16 partial PV
    float* __restrict__ attn_out)            // [B][8][N][N] (LAST only)
{
  int i0 = blockIdx.x * 32;
  int jc = blockIdx.y;
  int b  = blockIdx.z;
  int tid = threadIdx.x;
  int h = tid >> 6;            // wave index == head
  int l = tid & 63;
  int lr = l & 15, lg = l >> 4;
  __shared__ unsigned short pbuf[8 * 32 * 40];  // bf16, padded rows: BD -> exp -> P (20KB)

  // q fragments, direct from global (row-16B aligned)
  bf8v qf[2][2];
#pragma unroll
  for (int m = 0; m < 2; ++m)
#pragma unroll
    for (int ks = 0; ks < 2; ++ks)
      qf[m][ks] = *(const bf8v*)(qkv + (size_t)(b * 1024 + i0 + m * 16 + lr) * 1536 +
                                 h * 64 + ks * 32 + lg * 8);

  f4v oacc[2][4];
#pragma unroll
  for (int m = 0; m < 2; ++m)
#pragma unroll
    for (int dt = 0; dt < 4; ++dt) oacc[m][dt] = f4v{0.f, 0.f, 0.f, 0.f};

  for (int jt = 0; jt < 16; ++jt) {
    int j0 = jc * 512 + jt * 32;
    // coop load shifted BD tile (all heads) into pbuf: 2 x 16B per thread
#pragma unroll
    for (int e = 0; e < 2; ++e) {
      int id = e * 512 + tid;
      int jj8 = id & 3, row = (id >> 2) & 31, hh = id >> 7;
      bf8v vbd = *(const bf8v*)(bd + (((size_t)(b * 8 + hh)) << 20) +
                                (size_t)(i0 + row) * 1024 + j0 + jj8 * 8);
      *(bf8v*)&pbuf[(hh * 32 + row) * 40 + jj8 * 8] = vbd;
    }
    // AC MFMA (k fragments direct from global; L2-resident)
    bf8v kf[2][2];
#pragma unroll
    for (int n = 0; n < 2; ++n)
#pragma unroll
      for (int ks = 0; ks < 2; ++ks)
        kf[n][ks] = *(const bf8v*)(qkv + (size_t)(b * 1024 + j0 + n * 16 + lr) * 1536 +
                                   512 + h * 64 + ks * 32 + lg * 8);
    f4v dacc[2][2];
#pragma unroll
    for (int m = 0; m < 2; ++m)
#pragma unroll
      for (int n = 0; n < 2; ++n) {
        dacc[m][n] = f4v{0.f, 0.f, 0.f, 0.f};
#pragma unroll
        for (int ks = 0; ks < 2; ++ks)
          dacc[m][n] = MFMA16(qf[m][ks], kf[n][ks], dacc[m][n]);
      }
    __syncthreads();  // BD tile visible
    // owner lanes: dot=(AC+BD)*SCALE, exp (f32), write back in place
#pragma unroll
    for (int m = 0; m < 2; ++m)
#pragma unroll
      for (int n = 0; n < 2; ++n)
#pragma unroll
        for (int r = 0; r < 4; ++r) {
          int row = m * 16 + lg * 4 + r;
          int col = n * 16 + lr;
          int d = (j0 + col) - (i0 + row);
          float bdv = (d == 1) ? 0.0f : b2f(pbuf[(h * 32 + row) * 40 + col]);
          float dot = (dacc[m][n][r] + bdv) * 0.125f;
          pbuf[(h * 32 + row) * 40 + col] = f2b(__expf(dot));
        }
    __syncthreads();  // all exps visible
    // denominator over heads; normalize in place; last layer: write attention
#pragma unroll
    for (int e = 0; e < 2; ++e) {
      int p = e * 512 + tid;
      int ii = p >> 5, jj = p & 31;
      float ev[8], ssum = 0.f;
#pragma unroll
      for (int hh = 0; hh < 8; ++hh) { ev[hh] = b2f(pbuf[(hh * 32 + ii) * 40 + jj]); ssum += ev[hh]; }
      float inv = 1.0f / ssum;
#pragma unroll
      for (int hh = 0; hh < 8; ++hh) {
        float a = ev[hh] * inv;
        pbuf[(hh * 32 + ii) * 40 + jj] = f2b(a);
        if (LAST)
          attn_out[((size_t)(b * 8 + hh) * 1024 + i0 + ii) * 1024 + j0 + jj] = a;
      }
    }
    __syncthreads();  // P visible
    // PV MFMA: A = P rows, B = vt (direct global)
    bf8v pf[2];
#pragma unroll
    for (int m = 0; m < 2; ++m) pf[m] = *(bf8v*)&pbuf[(h * 32 + m * 16 + lr) * 40 + lg * 8];
#pragma unroll
    for (int dt = 0; dt < 4; ++dt) {
      bf8v vf = *(const bf8v*)(vt + (size_t)(b * 512 + h * 64 + dt * 16 + lr) * 1024 + j0 + lg * 8);
#pragma unroll
      for (int m = 0; m < 2; ++m) oacc[m][dt] = MFMA16(pf[m], vf, oacc[m][dt]);
    }
    __syncthreads();  // P consumed; pbuf free for next tile's BD
  }
  // write bf16 PV partials [jc][b][i][col]
#pragma unroll
  for (int m = 0; m < 2; ++m)
#pragma unroll
    for (int dt = 0; dt < 4; ++dt)
#pragma unroll
      for (int r = 0; r < 4; ++r) {
        int i = i0 + m * 16 + lg * 4 + r;
        int col = h * 64 + dt * 16 + lr;
        pvpart[((size_t)(jc * 8 + b) * 1024 + i) * 512 + col] = f2b(oacc[m][dt][r]);
      }
}

// ---------- reduce the 2 PV j-chunk partials -> bf16 attn output rows ----------
__global__ __launch_bounds__(256) void pvreduce_kernel(const unsigned short* __restrict__ part,
                                                       unsigned short* __restrict__ out) {
  size_t i = ((size_t)blockIdx.x * 256 + threadIdx.x) * 8;
  bf8v a = *(const bf8v*)(part + i);
  bf8v c = *(const bf8v*)(part + 4194304ull + i);
  bf8v o;
#pragma unroll
  for (int e = 0; e < 8; ++e) o[e] = (short)f2b(b2f((unsigned short)a[e]) + b2f((unsigned short)c[e]));
  *(bf8v*)(out + i) = o;
}

// =====================================================================================
extern "C" void kernel_launch(void* const* d_in, const int* in_sizes, int n_in,
                              void* d_out, int out_size, void* d_ws, size_t ws_size,
                              hipStream_t stream) {
  (void)in_sizes; (void)n_in; (void)out_size; (void)ws_size;
  const float* x_in   = (const float*)d_in[0];
  const float* r_t    = (const float*)d_in[1];
  const float* biaspf = (const float*)d_in[3];
  const float* ln1_g  = (const float*)d_in[4];
  const float* ln1_b  = (const float*)d_in[5];
  const float* Wqkv   = (const float*)d_in[6];
  const float* Wkr_t  = (const float*)d_in[7];
  const float* Wout   = (const float*)d_in[9];
  const float* bout   = (const float*)d_in[10];
  const float* ln2_g  = (const float*)d_in[11];
  const float* ln2_b  = (const float*)d_in[12];
  const float* W1     = (const float*)d_in[13];
  const float* b1     = (const float*)d_in[14];
  const float* W2     = (const float*)d_in[15];
  const float* b2     = (const float*)d_in[16];

  char* ws = (char*)d_ws;
  size_t off = 0;
  auto alloc = [&](size_t bytes) { char* p = ws + off; off += (bytes + 255) & ~(size_t)255; return p; };
  unsigned short* wt_qkv = (unsigned short*)alloc(4ull * 512 * 1536 * 2);
  unsigned short* wt_kr  = (unsigned short*)alloc(4ull * 512 * 512 * 2);
  unsigned short* wt_out = (unsigned short*)alloc(4ull * 512 * 512 * 2);
  unsigned short* wt_w1  = (unsigned short*)alloc(4ull * 512 * 2048 * 2);
  unsigned short* wt_w2  = (unsigned short*)alloc(4ull * 2048 * 512 * 2);
  unsigned short* rt_bf  = (unsigned short*)alloc(8192ull * 512 * 2);
  unsigned short* qkvb   = (unsigned short*)alloc(8192ull * 2048 * 2);  // union: qkv(1536) / ffh(2048)
  unsigned short* ffh    = qkvb;
  unsigned short* vtb    = (unsigned short*)alloc(8192ull * 512 * 2);
  unsigned short* bdb    = (unsigned short*)alloc(64ull * 1024 * 1024 * 2);  // shifted BD
  unsigned short* attnob = (unsigned short*)alloc(8192ull * 512 * 2);
  unsigned short* xn     = (unsigned short*)alloc(8192ull * 512 * 2);
  unsigned short* krb    = (unsigned short*)alloc(8192ull * 512 * 2);
  // pvpart (2 x 8.4MB bf16) aliases xn+krb: both dead during attention phase.
  unsigned short* pvpart = xn;

  float* x      = (float*)d_out;              // running residual lives in d_out x-region
  float* attn_o = (float*)d_out + 4194304;    // [B][H][N][N]

  hipMemcpyAsync(x, x_in, 4194304ull * 4, hipMemcpyDeviceToDevice, stream);

  // weights -> bf16 transposed (N,K); r_t -> bf16
  wconv_kernel<<<dim3(48, 16, 4), 256, 0, stream>>>(Wqkv, wt_qkv, 512, 1536);
  wconv_kernel<<<dim3(16, 16, 4), 256, 0, stream>>>(Wkr_t, wt_kr, 512, 512);
  wconv_kernel<<<dim3(16, 16, 4), 256, 0, stream>>>(Wout, wt_out, 512, 512);
  wconv_kernel<<<dim3(64, 16, 4), 256, 0, stream>>>(W1, wt_w1, 512, 2048);
  wconv_kernel<<<dim3(16, 64, 4), 256, 0, stream>>>(W2, wt_w2, 2048, 512);
  conv_kernel<<<2048, 256, 0, stream>>>(r_t, rt_bf, 8192 * 512 / 8);

  for (int lyr = 0; lyr < 4; ++lyr) {
    // LN1
    ln_kernel<<<2048, 256, 0, stream>>>(x, ln1_g + lyr * 512, ln1_b + lyr * 512, xn);
    // QKV (+bias_pf on q cols)
    gemm_kernel<EPI_QKV><<<dim3(12, 64, 1), 256, 0, stream>>>(
        xn, 512, 0, 0, wt_qkv + (size_t)lyr * 512 * 1536, 512, 0, 0,
        qkvb, 1536, 0, 512, biaspf, nullptr);
    // kr_t = r_t @ Wkr_t
    gemm_kernel<EPI_BF16><<<dim3(4, 64, 1), 256, 0, stream>>>(
        rt_bf, 512, 0, 0, wt_kr + (size_t)lyr * 512 * 512, 512, 0, 0,
        krb, 512, 0, 512, nullptr, nullptr);
    // v^T
    vtrans_kernel<<<dim3(32, 8, 8), 256, 0, stream>>>(qkvb, vtb);
    // BD (rel-shifted) = scatter(qb @ kr^T)   (batched z = b*8+h)
    gemm_kernel<EPI_SHIFT><<<dim3(8, 8, 64), 256, 0, stream>>>(
        qkvb, 1536, 1024l * 1536, 64, krb, 512, 1024l * 512, 64,
        bdb, 1024, 0, 64, nullptr, nullptr);
    // fused attention (j-chunked) + partial reduce
    if (lyr == 3)
      attn_kernel<true><<<dim3(32, 2, 8), 512, 0, stream>>>(qkvb, vtb, bdb, pvpart, attn_o);
    else
      attn_kernel<false><<<dim3(32, 2, 8), 512, 0, stream>>>(qkvb, vtb, bdb, pvpart, nullptr);
    pvreduce_kernel<<<2048, 256, 0, stream>>>(pvpart, attnob);
    // x = attn_out @ Wout + bout + x
    gemm_kernel<EPI_RES><<<dim3(4, 64, 1), 256, 0, stream>>>(
        attnob, 512, 0, 0, wt_out + (size_t)lyr * 512 * 512, 512, 0, 0,
        x, 512, 0, 512, bout + lyr * 512, x);
    // LN2
    ln_kernel<<<2048, 256, 0, stream>>>(x, ln2_g + lyr * 512, ln2_b + lyr * 512, xn);
    // h = gelu(xn2 @ W1 + b1)
    gemm_kernel<EPI_GELU><<<dim3(16, 64, 1), 256, 0, stream>>>(
        xn, 512, 0, 0, wt_w1 + (size_t)lyr * 512 * 2048, 512, 0, 0,
        ffh, 2048, 0, 512, b1 + lyr * 2048, nullptr);
    // x = h @ W2 + b2 + x
    gemm_kernel<EPI_RES><<<dim3(4, 64, 1), 256, 0, stream>>>(
        ffh, 2048, 0, 0, wt_w2 + (size_t)lyr * 2048 * 512, 2048, 0, 0,
        x, 512, 0, 2048, b2 + lyr * 512, x);
  }
}